// Round 15
// baseline (130.402 us; speedup 1.0000x reference)
//
#include <hip/hip_runtime.h>

#define N_NODES 50000
#define N_EDGES 800000
#define NE4 (N_EDGES / 4)
#define NMASKW 1568          // ceil(50000/32)=1563, padded
#define C1MAX 64             // unique layer-1 src cap (actual ~16)
#define CAP   16             // per-block dst==1 candidate cap
#define S2MAX 1024           // f2 slot cap (actual ~254)
#define DMAX  4096           // eD cap (actual ~256)
#define BK    96             // per-f2-slot bucket capacity (in-deg ~Poisson(16))
#define SB1   ((NE4 + 255) / 256)   // 782 scan1 blocks
#define GMEGA 512            // mega grid: low-VGPR scan phases, co-resident
#define FGRID 256            // slots kernel grid
#define SUBW  64             // counter stride in ints (256B apart)

#define AS(p, v)  __hip_atomic_store((p), (v), __ATOMIC_RELAXED, __HIP_MEMORY_SCOPE_AGENT)
#define ALD(p)    __hip_atomic_load((p), __ATOMIC_RELAXED, __HIP_MEMORY_SCOPE_AGENT)
#define AADD(p,v) __hip_atomic_fetch_add((p), (v), __ATOMIC_RELAXED, __HIP_MEMORY_SCOPE_AGENT)

__device__ __forceinline__ float lrelu(float v) { return v >= 0.f ? v : 0.01f * v; }
__device__ __forceinline__ bool mtest(const unsigned int* m, int i) {
    return (m[i >> 5] >> (i & 31)) & 1u;
}

// Distributed-release barrier: arrivals on 8 sub lines; 8 releasers bump top;
// the last releaser fans out to 8 per-sub RELEASE lines. Each block spins only
// on its own sub's release line (64 spinners/line, s_sleep(16) ~0.43us) ->
// ~16x less MALL spin traffic than a single shared release line.
__device__ __forceinline__ void gsyncM(int* sub, int* top, int* relArr, int ph) {
    __syncthreads();
    if (threadIdx.x == 0) {
        int s = blockIdx.x & 7;
        int old = AADD(&sub[s * SUBW], 1);
        if (old == ph * (GMEGA / 8) - 1) {
            int o2 = AADD(top, 1);
            if (o2 == ph * 8 - 1) {
#pragma unroll
                for (int i = 0; i < 8; ++i) AS(&relArr[i * SUBW], ph);
            }
        }
        while (ALD(&relArr[s * SUBW]) < ph) __builtin_amdgcn_s_sleep(16);
    }
    __syncthreads();
}

// ---- K1 (atomic-free): per-block dst==1 candidates + zero the shared zone ----
__global__ __launch_bounds__(256) void scan1_k(const int4* __restrict__ dst4,
                                               const int* __restrict__ src,
                                               int* __restrict__ e1cnt, int* __restrict__ e1val,
                                               unsigned int* __restrict__ zbase, int zwords) {
    __shared__ int lcnt;
    __shared__ int lval[CAP];
    const int tid = threadIdx.x;
    const int t = blockIdx.x * 256 + tid;
    if (tid == 0) lcnt = 0;
    __syncthreads();
    if (t < zwords) zbase[t] = 0u;               // cooperative zone zero (~41 KB)
    if (t < NE4) {
        int4 d4 = dst4[t];
        int dv[4] = { d4.x, d4.y, d4.z, d4.w };
#pragma unroll
        for (int k = 0; k < 4; ++k) {
            if (dv[k] == 1) {
                int q = atomicAdd(&lcnt, 1);     // LDS atomic
                if (q < CAP) lval[q] = src[t * 4 + k];
            }
        }
    }
    __syncthreads();
    int c = lcnt < CAP ? lcnt : CAP;
    if (tid == 0) e1cnt[blockIdx.x] = c;
    if (tid < c) e1val[blockIdx.x * CAP + tid] = lval[tid];
}

// ---- K2 mega: [P1 scan2] -bar- [P2 scan3] -bar- [P3 eDr remap + scan4] ----
struct PM {
    const int4* dst4; const int* src; const int4* src4; const float* x;
    const int* e1cnt; const int* e1val;
    unsigned int* f2m; unsigned int* f3m;
    int* pos2; int* cnt2; int2* eD; int* cntD; int* mult; int* cnt1g;
    float* agg0; int* bucket; int* slotCnt; int2* eDr;
    int* sub; int* top; int* relArr;
};

__global__ __launch_bounds__(256) void mega_k(PM p) {
    __shared__ unsigned int msk[NMASKW];
    __shared__ int candN[C1MAX];
    __shared__ int candC;
    const int tid = threadIdx.x;
    const int gid = blockIdx.x * 256 + tid;
    const int T = GMEGA * 256;

    // ---- P1: rebuild f1 in LDS; cnt1g + mult; f1[dst] -> eD; f2 first-setter -> pos2 ----
    for (int k = tid; k < NMASKW; k += 256) msk[k] = 0u;
    if (tid == 0) candC = 0;
    __syncthreads();
    for (int b = tid; b < SB1; b += 256) {            // gather candidates (3KB, L2-hot)
        int c = p.e1cnt[b]; if (c > CAP) c = CAP;
        for (int i = 0; i < c; ++i) {
            int n = p.e1val[b * CAP + i];
            unsigned int bit = 1u << (n & 31);
            unsigned int old = atomicOr(&msk[n >> 5], bit);   // LDS atomic
            if (!(old & bit)) { int q = atomicAdd(&candC, 1); if (q < C1MAX) candN[q] = n; }
        }
    }
    __syncthreads();
    int c1 = candC; if (c1 > C1MAX) c1 = C1MAX;
    if (blockIdx.x == 0 && tid == 0) AS(p.cnt1g, c1);
    for (int t = gid; t < NE4; t += T) {
        int4 d4 = p.dst4[t];
        int dv[4] = { d4.x, d4.y, d4.z, d4.w };
#pragma unroll
        for (int k = 0; k < 4; ++k) {
            int dd = dv[k];
            if (dd == 1) {                               // e1 edge: bump rank multiplicity
                int ss = p.src[t * 4 + k];
                int r = 0;
                for (int u = 0; u < c1; ++u) r += (candN[u] < ss);
                atomicAdd(&p.mult[r], 1);
            }
            if (mtest(msk, dd)) {
                int ss = p.src[t * 4 + k];
                unsigned int bit = 1u << (ss & 31);
                unsigned int old = atomicOr(&p.f2m[ss >> 5], bit);
                if (!(old & bit)) {
                    int q2 = atomicAdd(p.cnt2, 1);
                    if (q2 < S2MAX) AS(&p.pos2[ss], q2);
                }
                int r = 0;                               // slot1 = ascending-id rank
                for (int u = 0; u < c1; ++u) r += (candN[u] < dd);
                int q = atomicAdd(p.cntD, 1);
                if (q < DMAX) {
                    unsigned long long ev = (unsigned long long)(unsigned int)ss |
                                            ((unsigned long long)(unsigned int)r << 32);
                    AS((unsigned long long*)&p.eD[q], ev);
                }
            }
        }
    }
    gsyncM(p.sub, p.top, p.relArr, 1);

    // ---- P2: f2[dst] -> bucket[pos2[dst]]; f3 first-setter -> zero agg0[src] ----
    for (int k = tid; k < NMASKW; k += 256) msk[k] = p.f2m[k];
    __syncthreads();
    for (int t = gid; t < NE4; t += T) {
        int4 d4 = p.dst4[t];
        int dv[4] = { d4.x, d4.y, d4.z, d4.w };
#pragma unroll
        for (int k = 0; k < 4; ++k) {
            int dd = dv[k];
            if (mtest(msk, dd)) {
                int ss = p.src[t * 4 + k];
                unsigned int bit = 1u << (ss & 31);
                unsigned int old = atomicOr(&p.f3m[ss >> 5], bit);
                if (!(old & bit)) AS(&p.agg0[ss], 0.f);
                int sl = p.pos2[dd];
                if ((unsigned)sl < S2MAX) {
                    int bi = atomicAdd(&p.slotCnt[sl], 1);
                    if (bi < BK) AS(&p.bucket[sl * BK + bi], ss);
                }
            }
        }
    }
    gsyncM(p.sub, p.top, p.relArr, 2);

    // ---- P3: eDr remap + f3[dst] -> agg0 += x[src] ----
    {
        int cD = *p.cntD; if (cD > DMAX) cD = DMAX;
        if (gid < cD) {
            int2 e = p.eD[gid];                          // (src, rank1)
            int sl = p.pos2[e.x];
            unsigned long long ev =
                (unsigned long long)(unsigned int)((unsigned)sl < S2MAX ? sl : -1) |
                ((unsigned long long)(unsigned int)e.y << 32);
            AS((unsigned long long*)&p.eDr[gid], ev);
        }
    }
    for (int k = tid; k < NMASKW; k += 256) msk[k] = p.f3m[k];
    __syncthreads();
    for (int t = gid; t < NE4; t += T) {
        int4 d4 = p.dst4[t];
        bool m0 = mtest(msk, d4.x), m1 = mtest(msk, d4.y);
        bool m2 = mtest(msk, d4.z), m3 = mtest(msk, d4.w);
        if (m0 | m1 | m2 | m3) {
            int4 s4 = p.src4[t];
            if (m0) atomicAdd(&p.agg0[d4.x], p.x[s4.x]);
            if (m1) atomicAdd(&p.agg0[d4.y], p.x[s4.y]);
            if (m2) atomicAdd(&p.agg0[d4.z], p.x[s4.z]);
            if (m3) atomicAdd(&p.agg0[d4.w], p.x[s4.w]);
        }
    }
}

// ---- K3: block per f2-slot: bucket gather + row GEMM -> rowT; producer-side
//          gacc scatter; done-counter; last block runs the trivial tail ----
struct PS {
    const int* bucket; const int* slotCnt; const float* agg0;
    const float* W0; const float* b0; const float* W1; const float* b1; const float* W2;
    const float* b2; const float* W3; const float* b3;
    const int* cnt2; const int2* eDr; const int* cntD;
    const int* mult; const int* cnt1g;
    float* gacc; int* subD; int* topD; float* out;
};

__global__ __launch_bounds__(256) void slots_k(PS p) {
    __shared__ float xv[128];
    __shared__ float part[256];
    __shared__ float rowA[64];
    __shared__ float rowH[128];
    __shared__ float rowT[64];
    __shared__ float t3s[C1MAX];
    __shared__ int lflag;
    const int tid = threadIdx.x;
    const int g = tid >> 6, j = tid & 63;
    // independent prologue loads issued together (one waitcnt, not a chain)
    int c2 = *p.cnt2;
    int cD = *p.cntD;
    int myCnt0 = p.slotCnt[blockIdx.x];
    int bidx0 = (tid < BK) ? p.bucket[blockIdx.x * BK + tid] : 0;
    int2 e0 = p.eDr[tid];                                 // first scatter chunk (guarded later)
    if (c2 > S2MAX) c2 = S2MAX;
    if (cD > DMAX) cD = DMAX;
    const float w0 = p.W0[j], bb0 = p.b0[j];

    for (int b = blockIdx.x; b < c2; b += FGRID) {
        int cnt = (b == (int)blockIdx.x) ? myCnt0 : p.slotCnt[b];
        if (cnt > BK) cnt = BK;
        int bidx = (b == (int)blockIdx.x) ? bidx0
                 : ((tid < BK) ? p.bucket[b * BK + tid] : 0);
        if (tid < cnt) xv[tid] = p.agg0[bidx];            // parallel gather
        __syncthreads();
        float racc = 0.f;
        for (int m = g; m < cnt; m += 4) racc += lrelu(xv[m] * w0 + bb0);
        part[tid] = racc;
        __syncthreads();
        if (tid < 64)
            rowA[tid] = part[tid] + part[64 + tid] + part[128 + tid] + part[192 + tid];
        __syncthreads();
        if (tid < 128) {
            float h = p.b1[tid];
#pragma unroll
            for (int k = 0; k < 64; ++k) h += rowA[k] * p.W1[k * 128 + tid];
            rowH[tid] = lrelu(h);
        }
        __syncthreads();
        if (tid < 64) {
            float a2 = 0.f;
#pragma unroll
            for (int k = 0; k < 128; ++k) a2 += rowH[k] * p.W2[k * 64 + tid];
            rowT[tid] = a2;
        }
        __syncthreads();
        for (int base = 0; base < cD; base += 256) {      // producer-side scatter
            int i = base + tid;
            int2 e = (base == 0) ? e0 : make_int2(-1, -1);
            if (base != 0 && i < cD) e = p.eDr[i];
            bool m = (e.x == b) && (i < cD);
            unsigned long long bal = __ballot(m);
            while (bal) {
                int bit = __builtin_ctzll(bal); bal &= bal - 1;
                int sl1 = __shfl(e.y, bit, 64);
                if ((unsigned)sl1 < C1MAX)
                    atomicAdd(&p.gacc[sl1 * 64 + j], rowT[j]);
            }
        }
        __syncthreads();      // protect LDS before next slot
    }

    // -- hierarchical done: __syncthreads drains the block's atomics ----
    __syncthreads();
    if (tid == 0) {
        lflag = 0;
        int s = blockIdx.x & 7;
        int old = AADD(&p.subD[s * SUBW], 1);
        if (old == (FGRID / 8) - 1) {
            int o2 = AADD(p.topD, 1);
            lflag = (o2 == 7);
        }
    }
    __syncthreads();
    if (!lflag) return;

    // ---- trivial tail: O(c1) — gacc read + layer-4 + multiplicity sum ----
    {
        int c1 = *p.cnt1g; if (c1 > C1MAX) c1 = C1MAX;
        int w = tid >> 6;
        for (int r = w; r < c1; r += 4) {
            float v = lrelu(p.gacc[r * 64 + j] + p.b2[j]) * p.W3[j];
            for (int off = 32; off > 0; off >>= 1) v += __shfl_down(v, off, 64);
            if (j == 0) t3s[r] = v;
        }
        __syncthreads();
        if (tid == 0) {
            float s = 0.f;
            for (int r = 0; r < c1; ++r) s += (float)p.mult[r] * t3s[r];
            p.out[0] = lrelu(s + p.b3[0]);
        }
    }
}

extern "C" void kernel_launch(void* const* d_in, const int* in_sizes, int n_in,
                              void* d_out, int out_size, void* d_ws, size_t ws_size,
                              hipStream_t stream) {
    const float* x   = (const float*)d_in[0];
    const int*   src = (const int*)d_in[1];
    const int*   dst = (const int*)d_in[2];
    const float* W0 = (const float*)d_in[3];  const float* b0 = (const float*)d_in[4];
    const float* W1 = (const float*)d_in[5];  const float* b1 = (const float*)d_in[6];
    const float* W2 = (const float*)d_in[7];  const float* b2 = (const float*)d_in[8];
    const float* W3 = (const float*)d_in[9];  const float* b3 = (const float*)d_in[10];
    float* out = (float*)d_out;
    const int4* dst4 = (const int4*)dst;
    const int4* src4 = (const int4*)src;

    char* base = (char*)d_ws;
    size_t off = 0;
    auto take = [&](size_t bytes) { char* q = base + off; off += (bytes + 255) & ~(size_t)255; return q; };
    // ---- zone: zeroed by scan1 (contiguous plain stores, flushed at kernel end) ----
    unsigned int* f2m = (unsigned int*)take(NMASKW * 4);
    unsigned int* f3m = (unsigned int*)take(NMASKW * 4);
    int* cnt2  = (int*)take(4);
    int* cntD  = (int*)take(4);
    int* cnt1g = (int*)take(4);
    int* mult  = (int*)take((size_t)C1MAX * 4);
    int* sub   = (int*)take((size_t)8 * SUBW * 4);   // mega barrier arrivals
    int* top   = (int*)take(4);
    int* relArr= (int*)take((size_t)8 * SUBW * 4);   // mega per-sub release lines
    int* subD  = (int*)take((size_t)8 * SUBW * 4);   // slots done
    int* topD  = (int*)take(4);
    int* slotCnt = (int*)take((size_t)S2MAX * 4);
    float* gacc  = (float*)take((size_t)C1MAX * 64 * 4);
    int zwords = (int)(off / 4);
    // ---- uninitialized (written before read) ----
    float* agg0   = (float*)take((size_t)N_NODES * 4);
    int*   e1cnt  = (int*)take((size_t)SB1 * 4);
    int*   e1val  = (int*)take((size_t)SB1 * CAP * 4);
    int2*  eD     = (int2*)take((size_t)DMAX * 8);
    int2*  eDr    = (int2*)take((size_t)DMAX * 8);
    int*   bucket = (int*)take((size_t)S2MAX * BK * 4);
    int*   pos2   = (int*)take((size_t)N_NODES * 4);

    scan1_k<<<SB1, 256, 0, stream>>>(dst4, src, e1cnt, e1val, (unsigned int*)base, zwords);

    PM pm;
    pm.dst4 = dst4; pm.src = src; pm.src4 = src4; pm.x = x;
    pm.e1cnt = e1cnt; pm.e1val = e1val;
    pm.f2m = f2m; pm.f3m = f3m;
    pm.pos2 = pos2; pm.cnt2 = cnt2; pm.eD = eD; pm.cntD = cntD;
    pm.mult = mult; pm.cnt1g = cnt1g;
    pm.agg0 = agg0; pm.bucket = bucket; pm.slotCnt = slotCnt; pm.eDr = eDr;
    pm.sub = sub; pm.top = top; pm.relArr = relArr;
    mega_k<<<GMEGA, 256, 0, stream>>>(pm);

    PS hp;
    hp.bucket = bucket; hp.slotCnt = slotCnt; hp.agg0 = agg0;
    hp.W0 = W0; hp.b0 = b0; hp.W1 = W1; hp.b1 = b1; hp.W2 = W2;
    hp.b2 = b2; hp.W3 = W3; hp.b3 = b3;
    hp.cnt2 = cnt2; hp.eDr = eDr; hp.cntD = cntD;
    hp.mult = mult; hp.cnt1g = cnt1g;
    hp.gacc = gacc; hp.subD = subD; hp.topD = topD; hp.out = out;
    slots_k<<<FGRID, 256, 0, stream>>>(hp);
}

// Round 16
// 128.217 us; speedup vs baseline: 1.0170x; 1.0170x over previous
//
#include <hip/hip_runtime.h>

#define N_NODES 50000
#define N_EDGES 800000
#define NE4 (N_EDGES / 4)
#define NMASKW 1568          // ceil(50000/32)=1563, padded
#define C1MAX 64             // unique layer-1 src cap (actual ~16)
#define CAP   16             // per-block dst==1 candidate cap
#define S2MAX 1024           // f2 slot cap (actual ~254)
#define DMAX  4096           // eD cap (actual ~256)
#define BK    96             // per-f2-slot bucket capacity (in-deg ~Poisson(16))
#define SB1   ((NE4 + 255) / 256)   // 782 scan blocks
#define FGRID 256            // slots kernel grid (one scheduling wave)

#define AS(p, v)  __hip_atomic_store((p), (v), __ATOMIC_RELAXED, __HIP_MEMORY_SCOPE_AGENT)

__device__ __forceinline__ float lrelu(float v) { return v >= 0.f ? v : 0.01f * v; }
__device__ __forceinline__ bool mtest(const unsigned int* m, int i) {
    return (m[i >> 5] >> (i & 31)) & 1u;
}

// ---- K1 (atomic-free): per-block dst==1 candidates + zero the shared zone ----
__global__ __launch_bounds__(256) void scan1_k(const int4* __restrict__ dst4,
                                               const int* __restrict__ src,
                                               int* __restrict__ e1cnt, int* __restrict__ e1val,
                                               unsigned int* __restrict__ zbase, int zwords) {
    __shared__ int lcnt;
    __shared__ int lval[CAP];
    const int tid = threadIdx.x;
    const int t = blockIdx.x * 256 + tid;
    if (tid == 0) lcnt = 0;
    __syncthreads();
    if (t < zwords) zbase[t] = 0u;               // cooperative zone zero (~40 KB)
    if (t < NE4) {
        int4 d4 = dst4[t];
        int dv[4] = { d4.x, d4.y, d4.z, d4.w };
#pragma unroll
        for (int k = 0; k < 4; ++k) {
            if (dv[k] == 1) {
                int q = atomicAdd(&lcnt, 1);     // LDS atomic
                if (q < CAP) lval[q] = src[t * 4 + k];
            }
        }
    }
    __syncthreads();
    int c = lcnt < CAP ? lcnt : CAP;
    if (tid == 0) e1cnt[blockIdx.x] = c;
    if (tid < c) e1val[blockIdx.x * CAP + tid] = lval[tid];
}

// ---- K2: rebuild f1 in LDS; publish cnt1g + per-rank multiplicity; f1[dst] ->
//          eD=(src, rank1(dst)); f2 first-setter -> pos2 slot ----
__global__ __launch_bounds__(256) void scan2_k(const int4* __restrict__ dst4,
                                               const int* __restrict__ src,
                                               const int* __restrict__ e1cnt,
                                               const int* __restrict__ e1val,
                                               unsigned int* __restrict__ f2m,
                                               int* __restrict__ pos2, int* __restrict__ cnt2,
                                               int2* __restrict__ eD, int* __restrict__ cntD,
                                               int* __restrict__ mult, int* __restrict__ cnt1g) {
    __shared__ unsigned int msk[NMASKW];
    __shared__ int candN[C1MAX];
    __shared__ int candC;
    const int tid = threadIdx.x;
    for (int k = tid; k < NMASKW; k += 256) msk[k] = 0u;
    if (tid == 0) candC = 0;
    __syncthreads();
    for (int b = tid; b < SB1; b += 256) {            // gather candidates (3KB, L2-hot)
        int c = e1cnt[b]; if (c > CAP) c = CAP;
        for (int i = 0; i < c; ++i) {
            int n = e1val[b * CAP + i];
            unsigned int bit = 1u << (n & 31);
            unsigned int old = atomicOr(&msk[n >> 5], bit);   // LDS atomic
            if (!(old & bit)) { int q = atomicAdd(&candC, 1); if (q < C1MAX) candN[q] = n; }
        }
    }
    __syncthreads();
    int c1 = candC; if (c1 > C1MAX) c1 = C1MAX;
    if (blockIdx.x == 0 && tid == 0) AS(cnt1g, c1);
    int t = blockIdx.x * 256 + tid;
    if (t >= NE4) return;
    int4 d4 = dst4[t];
    int dv[4] = { d4.x, d4.y, d4.z, d4.w };
#pragma unroll
    for (int k = 0; k < 4; ++k) {
        int dd = dv[k];
        if (dd == 1) {                                   // e1 edge: bump rank multiplicity
            int ss = src[t * 4 + k];
            int r = 0;
            for (int u = 0; u < c1; ++u) r += (candN[u] < ss);
            atomicAdd(&mult[r], 1);
        }
        if (mtest(msk, dd)) {
            int ss = src[t * 4 + k];
            unsigned int bit = 1u << (ss & 31);
            unsigned int old = atomicOr(&f2m[ss >> 5], bit);
            if (!(old & bit)) {
                int q2 = atomicAdd(cnt2, 1);
                if (q2 < S2MAX) AS(&pos2[ss], q2);
            }
            int r = 0;                                   // slot1 = ascending-id rank
            for (int u = 0; u < c1; ++u) r += (candN[u] < dd);
            int q = atomicAdd(cntD, 1);
            if (q < DMAX) {
                unsigned long long ev = (unsigned long long)(unsigned int)ss |
                                        ((unsigned long long)(unsigned int)r << 32);
                AS((unsigned long long*)&eD[q], ev);
            }
        }
    }
}

// ---- K3: f2[dst] -> bucket[pos2[dst]] += src; f3 first-setter -> zero agg0[src] ----
__global__ __launch_bounds__(256) void scan3_k(const int4* __restrict__ dst4,
                                               const int* __restrict__ src,
                                               const unsigned int* __restrict__ f2m,
                                               unsigned int* __restrict__ f3m,
                                               const int* __restrict__ pos2,
                                               float* __restrict__ agg0,
                                               int* __restrict__ bucket,
                                               int* __restrict__ slotCnt) {
    __shared__ unsigned int msk[NMASKW];
    const int tid = threadIdx.x;
    for (int k = tid; k < NMASKW; k += 256) msk[k] = f2m[k];
    __syncthreads();
    int t = blockIdx.x * 256 + tid;
    if (t >= NE4) return;
    int4 d4 = dst4[t];
    int dv[4] = { d4.x, d4.y, d4.z, d4.w };
#pragma unroll
    for (int k = 0; k < 4; ++k) {
        int dd = dv[k];
        if (mtest(msk, dd)) {
            int ss = src[t * 4 + k];
            unsigned int bit = 1u << (ss & 31);
            unsigned int old = atomicOr(&f3m[ss >> 5], bit);
            if (!(old & bit)) AS(&agg0[ss], 0.f);
            int sl = pos2[dd];
            if ((unsigned)sl < S2MAX) {
                int bi = atomicAdd(&slotCnt[sl], 1);
                if (bi < BK) AS(&bucket[sl * BK + bi], ss);
            }
        }
    }
}

// ---- K4: f3[dst] -> agg0[dst] += x[src]; plus eDr remap (pos2 complete now) ----
__global__ __launch_bounds__(256) void scan4_k(const int4* __restrict__ dst4,
                                               const int4* __restrict__ src4,
                                               const float* __restrict__ x,
                                               const unsigned int* __restrict__ f3m,
                                               float* __restrict__ agg0,
                                               const int2* __restrict__ eD,
                                               const int* __restrict__ cntD,
                                               const int* __restrict__ pos2,
                                               int2* __restrict__ eDr) {
    __shared__ unsigned int msk[NMASKW];
    int g = blockIdx.x * 256 + threadIdx.x;
    {   // eDr[i] = (slot2(src), rank1) — parallel remap of the tiny eD list
        int cD = *cntD; if (cD > DMAX) cD = DMAX;
        if (g < cD) {
            int2 e = eD[g];
            int sl = pos2[e.x];
            unsigned long long ev =
                (unsigned long long)(unsigned int)((unsigned)sl < S2MAX ? sl : -1) |
                ((unsigned long long)(unsigned int)e.y << 32);
            AS((unsigned long long*)&eDr[g], ev);
        }
    }
    for (int k = threadIdx.x; k < NMASKW; k += 256) msk[k] = f3m[k];
    __syncthreads();
    if (g >= NE4) return;
    int4 d4 = dst4[g];
    bool m0 = mtest(msk, d4.x), m1 = mtest(msk, d4.y);
    bool m2 = mtest(msk, d4.z), m3 = mtest(msk, d4.w);
    if (m0 | m1 | m2 | m3) {
        int4 s4 = src4[g];
        if (m0) atomicAdd(&agg0[d4.x], x[s4.x]);
        if (m1) atomicAdd(&agg0[d4.y], x[s4.y]);
        if (m2) atomicAdd(&agg0[d4.z], x[s4.z]);
        if (m3) atomicAdd(&agg0[d4.w], x[s4.w]);
    }
}

// ---- K5: block per f2-slot: bucket gather + row GEMM 64->128->64 -> rowT;
//          producer-side gacc scatter. ----
struct PS {
    const int* bucket; const int* slotCnt; const float* agg0;
    const float* W0; const float* b0; const float* W1; const float* b1; const float* W2;
    const int* cnt2; const int2* eDr; const int* cntD;
    float* gacc;
};

__global__ __launch_bounds__(256) void slots_k(PS p) {
    __shared__ float xv[128];
    __shared__ float part[256];
    __shared__ float rowA[64];
    __shared__ float rowH[128];
    __shared__ float rowT[64];
    const int tid = threadIdx.x;
    const int g = tid >> 6, j = tid & 63;
    int c2 = *p.cnt2; if (c2 > S2MAX) c2 = S2MAX;
    int cD = *p.cntD; if (cD > DMAX) cD = DMAX;
    const float w0 = p.W0[j], bb0 = p.b0[j];

    for (int b = blockIdx.x; b < c2; b += FGRID) {
        // issue the first scatter-list chunk early — independent of the GEMM chain
        int2 e0 = make_int2(-1, -1);
        if (tid < cD) e0 = p.eDr[tid];
        int cnt = p.slotCnt[b]; if (cnt > BK) cnt = BK;
        if (tid < cnt) xv[tid] = p.agg0[p.bucket[b * BK + tid]];   // parallel gather
        __syncthreads();
        float racc = 0.f;
        for (int m = g; m < cnt; m += 4) racc += lrelu(xv[m] * w0 + bb0);
        part[tid] = racc;
        __syncthreads();
        if (tid < 64)
            rowA[tid] = part[tid] + part[64 + tid] + part[128 + tid] + part[192 + tid];
        __syncthreads();
        if (tid < 128) {
            float h = p.b1[tid];
#pragma unroll
            for (int k = 0; k < 64; ++k) h += rowA[k] * p.W1[k * 128 + tid];
            rowH[tid] = lrelu(h);
        }
        __syncthreads();
        if (tid < 64) {
            float a2 = 0.f;
#pragma unroll
            for (int k = 0; k < 128; ++k) a2 += rowH[k] * p.W2[k * 64 + tid];
            rowT[tid] = a2;
        }
        __syncthreads();
        for (int base = 0; base < cD; base += 256) {     // producer-side scatter
            int i = base + tid;
            int2 e = (base == 0) ? e0 : make_int2(-1, -1);
            if (base != 0 && i < cD) e = p.eDr[i];
            bool m = (e.x == b);
            unsigned long long bal = __ballot(m);
            while (bal) {
                int bit = __builtin_ctzll(bal); bal &= bal - 1;
                int sl1 = __shfl(e.y, bit, 64);
                if ((unsigned)sl1 < C1MAX)
                    atomicAdd(&p.gacc[sl1 * 64 + j], rowT[j]);
            }
        }
        __syncthreads();      // protect LDS before next slot
    }
}

// ---- K6 (tiny): t3[r] = sum_j lrelu(gacc[r][j]+b2[j])*W3[j]; out = lrelu(sum mult[r]*t3[r] + b3) ----
__global__ __launch_bounds__(256) void tail_k(const float* __restrict__ gacc,
                                              const int* __restrict__ mult,
                                              const int* __restrict__ cnt1g,
                                              const float* __restrict__ b2,
                                              const float* __restrict__ W3,
                                              const float* __restrict__ b3,
                                              float* __restrict__ out) {
    __shared__ float t3s[C1MAX];
    const int tid = threadIdx.x, j = tid & 63, w = tid >> 6;
    int c1 = *cnt1g; if (c1 > C1MAX) c1 = C1MAX;
    for (int r = w; r < c1; r += 4) {
        float v = lrelu(gacc[r * 64 + j] + b2[j]) * W3[j];
        for (int off = 32; off > 0; off >>= 1) v += __shfl_down(v, off, 64);
        if (j == 0) t3s[r] = v;
    }
    __syncthreads();
    if (tid == 0) {
        float s = 0.f;
        for (int r = 0; r < c1; ++r) s += (float)mult[r] * t3s[r];
        out[0] = lrelu(s + b3[0]);
    }
}

extern "C" void kernel_launch(void* const* d_in, const int* in_sizes, int n_in,
                              void* d_out, int out_size, void* d_ws, size_t ws_size,
                              hipStream_t stream) {
    const float* x   = (const float*)d_in[0];
    const int*   src = (const int*)d_in[1];
    const int*   dst = (const int*)d_in[2];
    const float* W0 = (const float*)d_in[3];  const float* b0 = (const float*)d_in[4];
    const float* W1 = (const float*)d_in[5];  const float* b1 = (const float*)d_in[6];
    const float* W2 = (const float*)d_in[7];  const float* b2 = (const float*)d_in[8];
    const float* W3 = (const float*)d_in[9];  const float* b3 = (const float*)d_in[10];
    float* out = (float*)d_out;
    const int4* dst4 = (const int4*)dst;
    const int4* src4 = (const int4*)src;

    char* base = (char*)d_ws;
    size_t off = 0;
    auto take = [&](size_t bytes) { char* q = base + off; off += (bytes + 255) & ~(size_t)255; return q; };
    // ---- zone: zeroed by scan1 (contiguous plain stores, flushed at kernel end) ----
    unsigned int* f2m = (unsigned int*)take(NMASKW * 4);
    unsigned int* f3m = (unsigned int*)take(NMASKW * 4);
    int* cnt2  = (int*)take(4);
    int* cntD  = (int*)take(4);
    int* cnt1g = (int*)take(4);
    int* mult  = (int*)take((size_t)C1MAX * 4);
    int* slotCnt = (int*)take((size_t)S2MAX * 4);
    float* gacc  = (float*)take((size_t)C1MAX * 64 * 4);
    int zwords = (int)(off / 4);
    // ---- uninitialized (written before read) ----
    float* agg0   = (float*)take((size_t)N_NODES * 4);
    int*   e1cnt  = (int*)take((size_t)SB1 * 4);
    int*   e1val  = (int*)take((size_t)SB1 * CAP * 4);
    int2*  eD     = (int2*)take((size_t)DMAX * 8);
    int2*  eDr    = (int2*)take((size_t)DMAX * 8);
    int*   bucket = (int*)take((size_t)S2MAX * BK * 4);
    int*   pos2   = (int*)take((size_t)N_NODES * 4);

    scan1_k<<<SB1, 256, 0, stream>>>(dst4, src, e1cnt, e1val, (unsigned int*)base, zwords);
    scan2_k<<<SB1, 256, 0, stream>>>(dst4, src, e1cnt, e1val, f2m, pos2, cnt2, eD, cntD,
                                     mult, cnt1g);
    scan3_k<<<SB1, 256, 0, stream>>>(dst4, src, f2m, f3m, pos2, agg0, bucket, slotCnt);
    scan4_k<<<SB1, 256, 0, stream>>>(dst4, src4, x, f3m, agg0, eD, cntD, pos2, eDr);

    PS hp;
    hp.bucket = bucket; hp.slotCnt = slotCnt; hp.agg0 = agg0;
    hp.W0 = W0; hp.b0 = b0; hp.W1 = W1; hp.b1 = b1; hp.W2 = W2;
    hp.cnt2 = cnt2; hp.eDr = eDr; hp.cntD = cntD; hp.gacc = gacc;
    slots_k<<<FGRID, 256, 0, stream>>>(hp);

    tail_k<<<1, 256, 0, stream>>>(gacc, mult, cnt1g, b2, W3, b3, out);
}